// Round 1
// baseline (103.422 us; speedup 1.0000x reference)
//
#include <hip/hip_runtime.h>
#include <math.h>

#define B 64
#define S 300
#define R 100
#define F 10

// weight offsets inside the LDS-staged weight block
#define L1W 0    // 5x15
#define L1B 75
#define L2W 80   // 5x5
#define L2B 105
#define L3W 110  // 5x5
#define L3B 135
#define FC1W 140 // 5x20
#define FC1B 240
#define FC2W 245 // 5x5
#define FC2B 270
#define FC3W 275 // 1x5
#define FC3B 280
#define NW 281

__device__ __forceinline__ float elu_f(float x) {
    return x > 0.f ? x : (__expf(x) - 1.f);
}

__global__ __launch_bounds__(128) void alt_pred_k1(
    const float* __restrict__ x,
    const float* __restrict__ l1_w, const float* __restrict__ l1_b,
    const float* __restrict__ l2_w, const float* __restrict__ l2_b,
    const float* __restrict__ l3_w, const float* __restrict__ l3_b,
    const float* __restrict__ fc1_w, const float* __restrict__ fc1_b,
    const float* __restrict__ fc2_w, const float* __restrict__ fc2_b,
    const float* __restrict__ fc3_w, const float* __restrict__ fc3_b,
    unsigned int* __restrict__ wsmax)
{
    __shared__ __align__(16) float xs[R * F];   // 1000 floats, 4 KB
    __shared__ float W[NW];
    __shared__ float red[128 * 5];              // stride-5: conflict-free tree

    const int tid = threadIdx.x;
    const int bid = blockIdx.x;                 // b*S + s
    const int b = bid / S;

    // ---- stage x tile: 1000 contiguous floats = 250 float4, coalesced ----
    {
        const float4* src = (const float4*)(x + (size_t)bid * (R * F));
        float4* dst = (float4*)xs;
        for (int i = tid; i < (R * F) / 4; i += 128) dst[i] = src[i];
    }
    // ---- stage weights ----
    for (int i = tid; i < 75;  i += 128) W[L1W + i] = l1_w[i];
    for (int i = tid; i < 5;   i += 128) W[L1B + i] = l1_b[i];
    for (int i = tid; i < 25;  i += 128) W[L2W + i] = l2_w[i];
    for (int i = tid; i < 5;   i += 128) W[L2B + i] = l2_b[i];
    for (int i = tid; i < 25;  i += 128) W[L3W + i] = l3_w[i];
    for (int i = tid; i < 5;   i += 128) W[L3B + i] = l3_b[i];
    for (int i = tid; i < 100; i += 128) W[FC1W + i] = fc1_w[i];
    for (int i = tid; i < 5;   i += 128) W[FC1B + i] = fc1_b[i];
    for (int i = tid; i < 25;  i += 128) W[FC2W + i] = fc2_w[i];
    for (int i = tid; i < 5;   i += 128) W[FC2B + i] = fc2_b[i];
    for (int i = tid; i < 5;   i += 128) W[FC3W + i] = fc3_w[i];
    if (tid == 0) W[FC3B] = fc3_b[0];
    __syncthreads();

    const bool act = (tid < R);
    float f[F];
#pragma unroll
    for (int i = 0; i < F; ++i) f[i] = act ? xs[tid * F + i] : 0.f;

    // dot with read-0 feats
    const float rdot = f[0]*xs[0] + f[1]*xs[1] + f[2]*xs[2] + f[3]*xs[3];

    // ---- block mean of f[0..3] over reads ----
#pragma unroll
    for (int k = 0; k < 4; ++k) red[tid * 5 + k] = f[k];
    __syncthreads();
    for (int s = 64; s > 0; s >>= 1) {
        if (tid < s) {
#pragma unroll
            for (int k = 0; k < 4; ++k) red[tid * 5 + k] += red[(tid + s) * 5 + k];
        }
        __syncthreads();
    }
    float bm[4];
#pragma unroll
    for (int k = 0; k < 4; ++k) bm[k] = red[k] * (1.f / R);
    __syncthreads();   // before red reuse

    // bx[15] = [bm(4), rdot, f(10)]
    float bx[15];
    bx[0]=bm[0]; bx[1]=bm[1]; bx[2]=bm[2]; bx[3]=bm[3]; bx[4]=rdot;
#pragma unroll
    for (int i = 0; i < F; ++i) bx[5 + i] = f[i];

    // ---- l1/l2/l3 residual chain (width 5) ----
    float y1[5];
#pragma unroll
    for (int o = 0; o < 5; ++o) {
        float acc = W[L1B + o];
#pragma unroll
        for (int k = 0; k < 15; ++k) acc += bx[k] * W[L1W + o * 15 + k];
        y1[o] = elu_f(acc);
    }
    float y2[5];
#pragma unroll
    for (int o = 0; o < 5; ++o) {
        float acc = W[L2B + o] + y1[o];
#pragma unroll
        for (int k = 0; k < 5; ++k) acc += y1[k] * W[L2W + o * 5 + k];
        y2[o] = elu_f(acc);
    }
    float y3[5];
#pragma unroll
    for (int o = 0; o < 5; ++o) {
        float acc = W[L3B + o] + y2[o];
#pragma unroll
        for (int k = 0; k < 5; ++k) acc += y2[k] * W[L3W + o * 5 + k];
        y3[o] = elu_f(acc);
    }

    // ---- block mean of y3 over reads ----
#pragma unroll
    for (int k = 0; k < 5; ++k) red[tid * 5 + k] = act ? y3[k] : 0.f;
    __syncthreads();
    for (int s = 64; s > 0; s >>= 1) {
        if (tid < s) {
#pragma unroll
            for (int k = 0; k < 5; ++k) red[tid * 5 + k] += red[(tid + s) * 5 + k];
        }
        __syncthreads();
    }
    float ym[5];
#pragma unroll
    for (int k = 0; k < 5; ++k) ym[k] = red[k] * (1.f / R);

    // z2[20] = [ym(5), bx(15)]
    float z2[20];
#pragma unroll
    for (int k = 0; k < 5; ++k) z2[k] = ym[k];
#pragma unroll
    for (int k = 0; k < 15; ++k) z2[5 + k] = bx[k];

    float h1[5];
#pragma unroll
    for (int o = 0; o < 5; ++o) {
        float acc = W[FC1B + o];
#pragma unroll
        for (int k = 0; k < 20; ++k) acc += z2[k] * W[FC1W + o * 20 + k];
        h1[o] = elu_f(acc);
    }
    float h2[5];
#pragma unroll
    for (int o = 0; o < 5; ++o) {
        float acc = W[FC2B + o] + h1[o];
#pragma unroll
        for (int k = 0; k < 5; ++k) acc += h1[k] * W[FC2W + o * 5 + k];
        h2[o] = elu_f(acc);
    }
    float acc = W[FC3B];
#pragma unroll
    for (int k = 0; k < 5; ++k) acc += h2[k] * W[FC3W + k];
    const float h = 5.f * elu_f(acc);

    if (act) {
        // monotone float->uint key; larger float => larger key
        unsigned int bits = __float_as_uint(h);
        unsigned int key = (bits & 0x80000000u) ? ~bits : (bits | 0x80000000u);
        atomicMax(&wsmax[b * R + tid], key);
    }
}

__global__ void alt_pred_k2(const unsigned int* __restrict__ wsmax,
                            float* __restrict__ out)
{
    const int i = blockIdx.x * blockDim.x + threadIdx.x;
    if (i < B * R) {
        const unsigned int key = wsmax[i];
        const unsigned int bits = (key & 0x80000000u) ? (key & 0x7FFFFFFFu) : ~key;
        const float h = __uint_as_float(bits);
        out[i] = 1.f / (1.f + __expf(-h));
    }
}

extern "C" void kernel_launch(void* const* d_in, const int* in_sizes, int n_in,
                              void* d_out, int out_size, void* d_ws, size_t ws_size,
                              hipStream_t stream) {
    const float* x     = (const float*)d_in[0];
    const float* l1_w  = (const float*)d_in[1];
    const float* l1_b  = (const float*)d_in[2];
    const float* l2_w  = (const float*)d_in[3];
    const float* l2_b  = (const float*)d_in[4];
    const float* l3_w  = (const float*)d_in[5];
    const float* l3_b  = (const float*)d_in[6];
    const float* fc1_w = (const float*)d_in[7];
    const float* fc1_b = (const float*)d_in[8];
    const float* fc2_w = (const float*)d_in[9];
    const float* fc2_b = (const float*)d_in[10];
    const float* fc3_w = (const float*)d_in[11];
    const float* fc3_b = (const float*)d_in[12];

    unsigned int* wsmax = (unsigned int*)d_ws;
    hipMemsetAsync(d_ws, 0, (size_t)B * R * sizeof(unsigned int), stream);

    alt_pred_k1<<<B * S, 128, 0, stream>>>(
        x, l1_w, l1_b, l2_w, l2_b, l3_w, l3_b,
        fc1_w, fc1_b, fc2_w, fc2_b, fc3_w, fc3_b, wsmax);

    alt_pred_k2<<<(B * R + 255) / 256, 256, 0, stream>>>(wsmax, (float*)d_out);
}

// Round 2
// 69.821 us; speedup vs baseline: 1.4812x; 1.4812x over previous
//
#include <hip/hip_runtime.h>
#include <math.h>

#define B 64
#define S 300
#define R 100
#define F 10
#define NTILE (B * S)   // 19200, divisible by 4

// weight offsets inside the LDS-staged weight block
#define L1W 0    // 5x15
#define L1B 75
#define L2W 80   // 5x5
#define L2B 105
#define L3W 110  // 5x5
#define L3B 135
#define FC1W 140 // 5x20
#define FC1B 240
#define FC2W 245 // 5x5
#define FC2B 270
#define FC3W 275 // 1x5
#define FC3B 280
#define NW 281

typedef float v2 __attribute__((ext_vector_type(2)));

__device__ __forceinline__ float elu1(float x) {
    return x > 0.f ? x : (__expf(x) - 1.f);
}
__device__ __forceinline__ v2 vsplat(float s) { v2 r; r.x = s; r.y = s; return r; }
__device__ __forceinline__ v2 fma2(v2 a, float b, v2 c) {
    return __builtin_elementwise_fma(a, vsplat(b), c);
}
__device__ __forceinline__ v2 elu2(v2 x) {
    v2 r; r.x = elu1(x.x); r.y = elu1(x.y); return r;
}
__device__ __forceinline__ float wsum(float v) {
#pragma unroll
    for (int m = 1; m < 64; m <<= 1) v += __shfl_xor(v, m, 64);
    return v;
}
__device__ __forceinline__ unsigned int fkey(float f) {
    unsigned int bits = __float_as_uint(f);
    return (bits & 0x80000000u) ? ~bits : (bits | 0x80000000u);
}

__global__ __launch_bounds__(256, 4) void alt_pred_k1(
    const float* __restrict__ x,
    const float* __restrict__ l1_w, const float* __restrict__ l1_b,
    const float* __restrict__ l2_w, const float* __restrict__ l2_b,
    const float* __restrict__ l3_w, const float* __restrict__ l3_b,
    const float* __restrict__ fc1_w, const float* __restrict__ fc1_b,
    const float* __restrict__ fc2_w, const float* __restrict__ fc2_b,
    const float* __restrict__ fc3_w, const float* __restrict__ fc3_b,
    unsigned int* __restrict__ wsmax)
{
    __shared__ __align__(16) float xs[4 * R * F];   // 4 tiles x 1000 floats
    __shared__ float W[NW];

    const int tid = threadIdx.x;

    // ---- stage 4 consecutive tiles: 4000 contiguous floats, coalesced ----
    {
        const float4* src = (const float4*)(x + (size_t)blockIdx.x * (4 * R * F));
        float4* dst = (float4*)xs;
#pragma unroll
        for (int i = 0; i < 4; ++i) {
            int idx = tid + 256 * i;
            if (idx < (4 * R * F) / 4) dst[idx] = src[idx];
        }
    }
    // ---- stage weights ----
    for (int i = tid; i < 75;  i += 256) W[L1W + i] = l1_w[i];
    for (int i = tid; i < 5;   i += 256) W[L1B + i] = l1_b[i];
    for (int i = tid; i < 25;  i += 256) W[L2W + i] = l2_w[i];
    for (int i = tid; i < 5;   i += 256) W[L2B + i] = l2_b[i];
    for (int i = tid; i < 25;  i += 256) W[L3W + i] = l3_w[i];
    for (int i = tid; i < 5;   i += 256) W[L3B + i] = l3_b[i];
    for (int i = tid; i < 100; i += 256) W[FC1W + i] = fc1_w[i];
    for (int i = tid; i < 5;   i += 256) W[FC1B + i] = fc1_b[i];
    for (int i = tid; i < 25;  i += 256) W[FC2W + i] = fc2_w[i];
    for (int i = tid; i < 5;   i += 256) W[FC2B + i] = fc2_b[i];
    for (int i = tid; i < 5;   i += 256) W[FC3W + i] = fc3_w[i];
    if (tid == 0) W[FC3B] = fc3_b[0];
    __syncthreads();   // the ONLY barrier

    const int wv = tid >> 6;
    const int lane = tid & 63;
    const int t = blockIdx.x * 4 + wv;      // tile = b*S + s
    const int b = t / S;
    const float* xt = xs + wv * (R * F);

    // lane handles reads r1 = lane (always valid) and r2 = lane+64 (lane<36)
    const bool a2 = (lane < 36);
    const int r1 = lane;
    const int r2 = a2 ? (lane + 64) : (R - 1);

    // load features as float2-of-(r1,r2)
    v2 f[F];
#pragma unroll
    for (int i = 0; i < F; i += 2) {
        float2 u1 = *(const float2*)(xt + r1 * F + i);
        float2 u2 = *(const float2*)(xt + r2 * F + i);
        f[i].x = u1.x; f[i].y = u2.x;
        f[i + 1].x = u1.y; f[i + 1].y = u2.y;
    }

    // rdot = dot(feat[0:4], read0 feat[0:4])
    float x00 = xt[0], x01 = xt[1], x02 = xt[2], x03 = xt[3];
    v2 rdot = fma2(f[0], x00, fma2(f[1], x01, fma2(f[2], x02, f[3] * vsplat(x03))));

    // ---- mean of feat[0:4] over 100 reads (shfl butterfly) ----
    float bm[4];
#pragma unroll
    for (int k = 0; k < 4; ++k) {
        float loc = f[k].x + (a2 ? f[k].y : 0.f);
        bm[k] = wsum(loc) * (1.f / R);
    }

    // ---- l1: input [bm(4), rdot, f(10)]; hoist uniform bm part ----
    float pre1[5];
#pragma unroll
    for (int o = 0; o < 5; ++o) {
        float acc = W[L1B + o];
#pragma unroll
        for (int k = 0; k < 4; ++k) acc = fmaf(bm[k], W[L1W + o * 15 + k], acc);
        pre1[o] = acc;
    }
    v2 y1[5];
#pragma unroll
    for (int o = 0; o < 5; ++o) {
        v2 acc = vsplat(pre1[o]);
        acc = fma2(rdot, W[L1W + o * 15 + 4], acc);
#pragma unroll
        for (int k = 0; k < F; ++k) acc = fma2(f[k], W[L1W + o * 15 + 5 + k], acc);
        y1[o] = elu2(acc);
    }
    // ---- l2 (+residual) ----
    v2 y2[5];
#pragma unroll
    for (int o = 0; o < 5; ++o) {
        v2 acc = vsplat(W[L2B + o]) + y1[o];
#pragma unroll
        for (int k = 0; k < 5; ++k) acc = fma2(y1[k], W[L2W + o * 5 + k], acc);
        y2[o] = elu2(acc);
    }
    // ---- l3 (+residual) ----
    v2 y3[5];
#pragma unroll
    for (int o = 0; o < 5; ++o) {
        v2 acc = vsplat(W[L3B + o]) + y2[o];
#pragma unroll
        for (int k = 0; k < 5; ++k) acc = fma2(y2[k], W[L3W + o * 5 + k], acc);
        y3[o] = elu2(acc);
    }

    // ---- mean of y3 over 100 reads ----
    float ym[5];
#pragma unroll
    for (int k = 0; k < 5; ++k) {
        float loc = y3[k].x + (a2 ? y3[k].y : 0.f);
        ym[k] = wsum(loc) * (1.f / R);
    }

    // ---- fc1: input [ym(5), bm(4), rdot, f(10)]; hoist uniform ym+bm ----
    float pre2[5];
#pragma unroll
    for (int o = 0; o < 5; ++o) {
        float acc = W[FC1B + o];
#pragma unroll
        for (int k = 0; k < 5; ++k) acc = fmaf(ym[k], W[FC1W + o * 20 + k], acc);
#pragma unroll
        for (int k = 0; k < 4; ++k) acc = fmaf(bm[k], W[FC1W + o * 20 + 5 + k], acc);
        pre2[o] = acc;
    }
    v2 h1[5];
#pragma unroll
    for (int o = 0; o < 5; ++o) {
        v2 acc = vsplat(pre2[o]);
        acc = fma2(rdot, W[FC1W + o * 20 + 9], acc);
#pragma unroll
        for (int k = 0; k < F; ++k) acc = fma2(f[k], W[FC1W + o * 20 + 10 + k], acc);
        h1[o] = elu2(acc);
    }
    // ---- fc2 (+residual) ----
    v2 h2[5];
#pragma unroll
    for (int o = 0; o < 5; ++o) {
        v2 acc = vsplat(W[FC2B + o]) + h1[o];
#pragma unroll
        for (int k = 0; k < 5; ++k) acc = fma2(h1[k], W[FC2W + o * 5 + k], acc);
        h2[o] = elu2(acc);
    }
    // ---- fc3 raw accumulator (sigmoid(5*elu(.)) is monotone -> max commutes) ----
    v2 hacc = vsplat(W[FC3B]);
#pragma unroll
    for (int k = 0; k < 5; ++k) hacc = fma2(h2[k], W[FC3W + k], hacc);

    atomicMax(&wsmax[b * R + r1], fkey(hacc.x));
    if (a2) atomicMax(&wsmax[b * R + lane + 64], fkey(hacc.y));
}

__global__ void alt_pred_k2(const unsigned int* __restrict__ wsmax,
                            float* __restrict__ out)
{
    const int i = blockIdx.x * blockDim.x + threadIdx.x;
    if (i < B * R) {
        const unsigned int key = wsmax[i];
        const unsigned int bits = (key & 0x80000000u) ? (key & 0x7FFFFFFFu) : ~key;
        const float acc = __uint_as_float(bits);
        const float h = 5.f * elu1(acc);
        out[i] = 1.f / (1.f + __expf(-h));
    }
}

extern "C" void kernel_launch(void* const* d_in, const int* in_sizes, int n_in,
                              void* d_out, int out_size, void* d_ws, size_t ws_size,
                              hipStream_t stream) {
    const float* x     = (const float*)d_in[0];
    const float* l1_w  = (const float*)d_in[1];
    const float* l1_b  = (const float*)d_in[2];
    const float* l2_w  = (const float*)d_in[3];
    const float* l2_b  = (const float*)d_in[4];
    const float* l3_w  = (const float*)d_in[5];
    const float* l3_b  = (const float*)d_in[6];
    const float* fc1_w = (const float*)d_in[7];
    const float* fc1_b = (const float*)d_in[8];
    const float* fc2_w = (const float*)d_in[9];
    const float* fc2_b = (const float*)d_in[10];
    const float* fc3_w = (const float*)d_in[11];
    const float* fc3_b = (const float*)d_in[12];

    unsigned int* wsmax = (unsigned int*)d_ws;
    hipMemsetAsync(d_ws, 0, (size_t)B * R * sizeof(unsigned int), stream);

    alt_pred_k1<<<NTILE / 4, 256, 0, stream>>>(
        x, l1_w, l1_b, l2_w, l2_b, l3_w, l3_b,
        fc1_w, fc1_b, fc2_w, fc2_b, fc3_w, fc3_b, wsmax);

    alt_pred_k2<<<(B * R + 255) / 256, 256, 0, stream>>>(wsmax, (float*)d_out);
}

// Round 3
// 55.124 us; speedup vs baseline: 1.8762x; 1.2666x over previous
//
#include <hip/hip_runtime.h>
#include <math.h>

#define B 64
#define S 300
#define R 100
#define F 10
#define NTILE (B * S)   // 19200, divisible by 4

typedef float v2 __attribute__((ext_vector_type(2)));

__device__ __forceinline__ v2 vsplat(float s) { v2 r; r.x = s; r.y = s; return r; }
__device__ __forceinline__ v2 fma2(v2 a, float b, v2 c) {
    return __builtin_elementwise_fma(a, vsplat(b), c);
}
// elu(x) = max(x, exp(min(x,0)) - 1): packed min/add/max, 2 scalar exps
__device__ __forceinline__ v2 elu2(v2 x) {
    v2 xm = __builtin_elementwise_min(x, vsplat(0.f));
    v2 e; e.x = __expf(xm.x); e.y = __expf(xm.y);
    return __builtin_elementwise_max(x, e - vsplat(1.f));
}
__device__ __forceinline__ float wsum(float v) {
#pragma unroll
    for (int m = 1; m < 64; m <<= 1) v += __shfl_xor(v, m, 64);
    return v;
}
__device__ __forceinline__ unsigned int fkey(float f) {
    unsigned int bits = __float_as_uint(f);
    return (bits & 0x80000000u) ? ~bits : (bits | 0x80000000u);
}
// wave-uniform lane-0 read -> SGPR
__device__ __forceinline__ float rdlane0(float v) {
    return __uint_as_float(__builtin_amdgcn_readlane(__float_as_uint(v), 0));
}

__global__ __launch_bounds__(256) void alt_pred_k1(
    const float* __restrict__ x,
    const float* __restrict__ l1_w, const float* __restrict__ l1_b,
    const float* __restrict__ l2_w, const float* __restrict__ l2_b,
    const float* __restrict__ l3_w, const float* __restrict__ l3_b,
    const float* __restrict__ fc1_w, const float* __restrict__ fc1_b,
    const float* __restrict__ fc2_w, const float* __restrict__ fc2_b,
    const float* __restrict__ fc3_w, const float* __restrict__ fc3_b,
    unsigned int* __restrict__ wsmax)
{
    const int tid = threadIdx.x;
    const int wv = tid >> 6;
    const int lane = tid & 63;
    const int t = blockIdx.x * 4 + wv;      // tile = b*S + s; one tile per wave
    const int b = t / S;
    const float* xt = x + (size_t)t * (R * F);

    // lane handles reads r1 = lane and r2 = lane+64 (dup masked for lane>=36)
    const bool a2 = (lane < R - 64);
    const int r2 = a2 ? (lane + 64) : (R - 1);

    // per-lane direct global loads: 5 float2 per read (8B aligned, F=10)
    v2 f[F];
    {
        const float2* p1 = (const float2*)(xt + lane * F);
        const float2* p2 = (const float2*)(xt + r2 * F);
#pragma unroll
        for (int i = 0; i < F; i += 2) {
            float2 u1 = p1[i >> 1];
            float2 u2 = p2[i >> 1];
            f[i].x = u1.x;     f[i].y = u2.x;
            f[i + 1].x = u1.y; f[i + 1].y = u2.y;
        }
    }

    // read-0 feats (lane 0 holds read 0 in .x) -> SGPRs
    const float x00 = rdlane0(f[0].x);
    const float x01 = rdlane0(f[1].x);
    const float x02 = rdlane0(f[2].x);
    const float x03 = rdlane0(f[3].x);
    v2 rdot = fma2(f[0], x00, fma2(f[1], x01, fma2(f[2], x02, f[3] * vsplat(x03))));

    // ---- mean of feat[0:4] over 100 reads (shfl butterfly) ----
    float bm[4];
#pragma unroll
    for (int k = 0; k < 4; ++k) {
        float loc = f[k].x + (a2 ? f[k].y : 0.f);
        bm[k] = wsum(loc) * (1.f / R);
    }

    // ---- l1: input [bm(4), rdot, f(10)]; weights are uniform s_loads ----
    float pre1[5];
#pragma unroll
    for (int o = 0; o < 5; ++o) {
        float acc = l1_b[o];
#pragma unroll
        for (int k = 0; k < 4; ++k) acc = fmaf(bm[k], l1_w[o * 15 + k], acc);
        pre1[o] = acc;
    }
    v2 y1[5];
#pragma unroll
    for (int o = 0; o < 5; ++o) {
        v2 acc = vsplat(pre1[o]);
        acc = fma2(rdot, l1_w[o * 15 + 4], acc);
#pragma unroll
        for (int k = 0; k < F; ++k) acc = fma2(f[k], l1_w[o * 15 + 5 + k], acc);
        y1[o] = elu2(acc);
    }
    // ---- l2 (+residual) ----
    v2 y2[5];
#pragma unroll
    for (int o = 0; o < 5; ++o) {
        v2 acc = vsplat(l2_b[o]) + y1[o];
#pragma unroll
        for (int k = 0; k < 5; ++k) acc = fma2(y1[k], l2_w[o * 5 + k], acc);
        y2[o] = elu2(acc);
    }
    // ---- l3 (+residual) ----
    v2 y3[5];
#pragma unroll
    for (int o = 0; o < 5; ++o) {
        v2 acc = vsplat(l3_b[o]) + y2[o];
#pragma unroll
        for (int k = 0; k < 5; ++k) acc = fma2(y2[k], l3_w[o * 5 + k], acc);
        y3[o] = elu2(acc);
    }

    // ---- mean of y3 over 100 reads ----
    float ym[5];
#pragma unroll
    for (int k = 0; k < 5; ++k) {
        float loc = y3[k].x + (a2 ? y3[k].y : 0.f);
        ym[k] = wsum(loc) * (1.f / R);
    }

    // ---- fc1: input [ym(5), bm(4), rdot, f(10)] ----
    float pre2[5];
#pragma unroll
    for (int o = 0; o < 5; ++o) {
        float acc = fc1_b[o];
#pragma unroll
        for (int k = 0; k < 5; ++k) acc = fmaf(ym[k], fc1_w[o * 20 + k], acc);
#pragma unroll
        for (int k = 0; k < 4; ++k) acc = fmaf(bm[k], fc1_w[o * 20 + 5 + k], acc);
        pre2[o] = acc;
    }
    v2 h1[5];
#pragma unroll
    for (int o = 0; o < 5; ++o) {
        v2 acc = vsplat(pre2[o]);
        acc = fma2(rdot, fc1_w[o * 20 + 9], acc);
#pragma unroll
        for (int k = 0; k < F; ++k) acc = fma2(f[k], fc1_w[o * 20 + 10 + k], acc);
        h1[o] = elu2(acc);
    }
    // ---- fc2 (+residual) ----
    v2 h2[5];
#pragma unroll
    for (int o = 0; o < 5; ++o) {
        v2 acc = vsplat(fc2_b[o]) + h1[o];
#pragma unroll
        for (int k = 0; k < 5; ++k) acc = fma2(h1[k], fc2_w[o * 5 + k], acc);
        h2[o] = elu2(acc);
    }
    // ---- fc3 raw accumulator (sigmoid(5*elu(.)) monotone -> max commutes) ----
    v2 hacc = vsplat(fc3_b[0]);
#pragma unroll
    for (int k = 0; k < 5; ++k) hacc = fma2(h2[k], fc3_w[k], hacc);

    atomicMax(&wsmax[b * R + lane], fkey(hacc.x));
    if (a2) atomicMax(&wsmax[b * R + lane + 64], fkey(hacc.y));
}

__global__ void alt_pred_k2(const unsigned int* __restrict__ wsmax,
                            float* __restrict__ out)
{
    const int i = blockIdx.x * blockDim.x + threadIdx.x;
    if (i < B * R) {
        const unsigned int key = wsmax[i];
        const unsigned int bits = (key & 0x80000000u) ? (key & 0x7FFFFFFFu) : ~key;
        const float acc = __uint_as_float(bits);
        const float h = 5.f * (acc > 0.f ? acc : (__expf(acc) - 1.f));
        out[i] = 1.f / (1.f + __expf(-h));
    }
}

extern "C" void kernel_launch(void* const* d_in, const int* in_sizes, int n_in,
                              void* d_out, int out_size, void* d_ws, size_t ws_size,
                              hipStream_t stream) {
    const float* x     = (const float*)d_in[0];
    const float* l1_w  = (const float*)d_in[1];
    const float* l1_b  = (const float*)d_in[2];
    const float* l2_w  = (const float*)d_in[3];
    const float* l2_b  = (const float*)d_in[4];
    const float* l3_w  = (const float*)d_in[5];
    const float* l3_b  = (const float*)d_in[6];
    const float* fc1_w = (const float*)d_in[7];
    const float* fc1_b = (const float*)d_in[8];
    const float* fc2_w = (const float*)d_in[9];
    const float* fc2_b = (const float*)d_in[10];
    const float* fc3_w = (const float*)d_in[11];
    const float* fc3_b = (const float*)d_in[12];

    unsigned int* wsmax = (unsigned int*)d_ws;
    hipMemsetAsync(d_ws, 0, (size_t)B * R * sizeof(unsigned int), stream);

    alt_pred_k1<<<NTILE / 4, 256, 0, stream>>>(
        x, l1_w, l1_b, l2_w, l2_b, l3_w, l3_b,
        fc1_w, fc1_b, fc2_w, fc2_b, fc3_w, fc3_b, wsmax);

    alt_pred_k2<<<(B * R + 255) / 256, 256, 0, stream>>>(wsmax, (float*)d_out);
}